// Round 1
// baseline (42.069 us; speedup 1.0000x reference)
//
#include <hip/hip_runtime.h>
#include <math.h>

typedef __attribute__((ext_vector_type(8))) short short8;
typedef __attribute__((ext_vector_type(4))) float f32x4;

__device__ __forceinline__ unsigned short f2bf(float x) {
    unsigned u = __float_as_uint(x);
    u += 0x7FFFu + ((u >> 16) & 1u);   // round-to-nearest-even
    return (unsigned short)(u >> 16);
}

// Pre-swizzle W2 (256x256 f32, row-major k x col) into bf16 MFMA B-fragment order:
// frag id f = (kt*16 + ct)*64 + l ; element j = B[kt*32 + (l>>4)*8 + j][ct*16 + (l&15)]
__global__ void w2prep_kernel(const float* __restrict__ W2, unsigned short* __restrict__ W2p) {
    int f = blockIdx.x * 256 + threadIdx.x;      // 0..8191
    int l = f & 63;
    int ct = (f >> 6) & 15;
    int kt = f >> 10;
    int col  = ct * 16 + (l & 15);
    int krow = kt * 32 + ((l >> 4) * 8);
    short8 v;
#pragma unroll
    for (int j = 0; j < 8; ++j) v[j] = (short)f2bf(W2[(krow + j) * 256 + col]);
    *reinterpret_cast<short8*>(W2p + (size_t)f * 8) = v;
}

__global__ __launch_bounds__(512) void actor_kernel(
    const float* __restrict__ obs,  const float* __restrict__ obst,
    const float* __restrict__ eps,  const float* __restrict__ W1,
    const float* __restrict__ b1,   const float* __restrict__ b2,
    const float* __restrict__ muW,  const float* __restrict__ mub,
    const float* __restrict__ lsW,  const float* __restrict__ lsb,
    const unsigned short* __restrict__ W2p, float* __restrict__ out)
{
    __shared__ __align__(16) short sA[2][16384];     // 2 x (256 rows x 64 k) bf16, swizzled, 64 KB
    __shared__ __align__(16) float sObstT[256][4];
    __shared__ float sMask[256];
    __shared__ float sVehW1[256];
    __shared__ __align__(16) float sW1oT[256][4];
    __shared__ float sB2[256];
    __shared__ float sPool[2][256];
    __shared__ float sObs[16];
    __shared__ float sPooled[256];

    const int b = blockIdx.x;
    const int t = threadIdx.x;
    const int l = t & 63;
    const int w = t >> 6;
    const int mi = w >> 2;    // 0..1 : row group (128 rows)
    const int ci = w & 3;     // 0..3 : col group (64 cols)

    // ---- phase 0: stage per-batch data ----
    if (t < 15) sObs[t] = obs[b * 15 + t];
    for (int i = t; i < 1280; i += 512) {             // obstacles[b] : 5 x 256
        float v = obst[b * 1280 + i];
        int c = i >> 8, n = i & 255;
        if (c < 4) sObstT[n][c] = v; else sMask[n] = v;
    }
    for (int i = t; i < 1024; i += 512) {             // W1 rows 15..18, transposed
        int c = i >> 8, j = i & 255;
        sW1oT[j][c] = W1[(15 + c) * 256 + j];
    }
    __syncthreads();
    if (t < 256) {                                    // veh @ W1[:15] + b1 (per-batch)
        float a = b1[t];
#pragma unroll
        for (int i = 0; i < 15; ++i) a = fmaf(sObs[i], W1[i * 256 + t], a);
        sVehW1[t] = a;
        sB2[t] = b2[t];
    }
    __syncthreads();

    const int n_thr = t & 255;
    const int jh    = (t >> 8) * 32;
    const float o0 = sObstT[n_thr][0], o1 = sObstT[n_thr][1];
    const float o2 = sObstT[n_thr][2], o3 = sObstT[n_thr][3];
    const unsigned swz_w = (unsigned)((n_thr & 7) << 4);

    f32x4 acc[8][4];
#pragma unroll
    for (int m = 0; m < 8; ++m)
#pragma unroll
        for (int c = 0; c < 4; ++c) acc[m][c] = (f32x4){0.f, 0.f, 0.f, 0.f};

    // layer-1 slice: h1[n][s*64 .. s*64+64) -> bf16 into sA[buf], swizzled rows of 128 B
    auto computeSlice = [&](int s, int buf) {
        char* base = (char*)&sA[buf][0] + n_thr * 128;
#pragma unroll
        for (int g = 0; g < 4; ++g) {
            short8 hv;
#pragma unroll
            for (int u = 0; u < 8; ++u) {
                int j = s * 64 + jh + g * 8 + u;
                float4 wv = *(const float4*)&sW1oT[j][0];
                float v = sVehW1[j];
                v = fmaf(o0, wv.x, v);
                v = fmaf(o1, wv.y, v);
                v = fmaf(o2, wv.z, v);
                v = fmaf(o3, wv.w, v);
                v = fmaxf(v, 0.f);
                hv[u] = (short)f2bf(v);
            }
            unsigned off = ((unsigned)((jh + g * 8) * 2)) ^ swz_w;
            *reinterpret_cast<short8*>(base + off) = hv;
        }
    };

    computeSlice(0, 0);
    __syncthreads();

    for (int s = 0; s < 4; ++s) {
        int buf = s & 1;
        if (s < 3) computeSlice(s + 1, buf ^ 1);      // VALU, overlaps MFMA pipe
#pragma unroll
        for (int kk = 0; kk < 2; ++kk) {
            short8 bfr[4];
            int kt = s * 2 + kk;
#pragma unroll
            for (int c = 0; c < 4; ++c) {
                int ct = ci * 4 + c;
                bfr[c] = *reinterpret_cast<const short8*>(W2p + (size_t)(((kt * 16 + ct) * 64 + l) * 8));
            }
#pragma unroll
            for (int m = 0; m < 8; ++m) {
                int n = mi * 128 + m * 16 + (l & 15);
                unsigned off = (unsigned)(n * 128) +
                               (((unsigned)(kk * 64 + ((l >> 4) * 16))) ^ ((unsigned)((n & 7) << 4)));
                short8 afr = *reinterpret_cast<const short8*>((char*)&sA[buf][0] + off);
#pragma unroll
                for (int c = 0; c < 4; ++c)
                    acc[m][c] = __builtin_amdgcn_mfma_f32_16x16x32_bf16(afr, bfr[c], acc[m][c], 0, 0, 0);
            }
        }
        __syncthreads();
    }

    // ---- masked pooling: pooled[col] = sum_n mask[n]*relu(h2[n][col]) ----
#pragma unroll
    for (int c = 0; c < 4; ++c) {
        int col = ci * 64 + c * 16 + (l & 15);
        float bb = sB2[col];
        float p = 0.f;
#pragma unroll
        for (int m = 0; m < 8; ++m) {
            int r0 = mi * 128 + m * 16 + ((l >> 4) * 4);
            f32x4 v = acc[m][c];
            p = fmaf(sMask[r0 + 0], fmaxf(v[0] + bb, 0.f), p);
            p = fmaf(sMask[r0 + 1], fmaxf(v[1] + bb, 0.f), p);
            p = fmaf(sMask[r0 + 2], fmaxf(v[2] + bb, 0.f), p);
            p = fmaf(sMask[r0 + 3], fmaxf(v[3] + bb, 0.f), p);
        }
        p += __shfl_xor(p, 16);
        p += __shfl_xor(p, 32);
        if ((l >> 4) == 0) sPool[mi][col] = p;
    }
    __syncthreads();
    if (t < 256) sPooled[t] = sPool[0][t] + sPool[1][t];
    __syncthreads();

    // ---- head (wave 0) ----
    if (t < 64) {
        float m0 = 0.f, m1 = 0.f, s0 = 0.f, s1 = 0.f;
#pragma unroll
        for (int hh = 0; hh < 4; ++hh) {
            int h = t + hh * 64;
            float p = sPooled[h];
            m0 = fmaf(p, muW[h * 2 + 0], m0);
            m1 = fmaf(p, muW[h * 2 + 1], m1);
            s0 = fmaf(p, lsW[h * 2 + 0], s0);
            s1 = fmaf(p, lsW[h * 2 + 1], s1);
        }
#pragma unroll
        for (int off = 32; off > 0; off >>= 1) {
            m0 += __shfl_xor(m0, off);
            m1 += __shfl_xor(m1, off);
            s0 += __shfl_xor(s0, off);
            s1 += __shfl_xor(s1, off);
        }
        if (t == 0) {
            float mu0 = m0 + mub[0], mu1 = m1 + mub[1];
            float ls0 = fminf(fmaxf(s0 + lsb[0], -20.f), 2.f);
            float ls1 = fminf(fmaxf(s1 + lsb[1], -20.f), 2.f);
            float e0 = eps[b * 2 + 0], e1 = eps[b * 2 + 1];
            float a0 = fmaf(expf(ls0), e0, mu0);
            float a1 = fmaf(expf(ls1), e1, mu1);
            float logp = -0.5f * (e0 * e0 + e1 * e1) - (ls0 + ls1) - 1.8378770664093453f;
            float x0 = -2.f * a0, x1 = -2.f * a1;
            float sp0 = fmaxf(x0, 0.f) + log1pf(expf(-fabsf(x0)));
            float sp1 = fmaxf(x1, 0.f) + log1pf(expf(-fabsf(x1)));
            logp -= 2.f * (0.6931471805599453f - a0 - sp0);
            logp -= 2.f * (0.6931471805599453f - a1 - sp1);
            out[b * 2 + 0] = tanhf(a0);
            out[b * 2 + 1] = tanhf(a1);
            out[1024 + b] = logp;
        }
    }
}

extern "C" void kernel_launch(void* const* d_in, const int* in_sizes, int n_in,
                              void* d_out, int out_size, void* d_ws, size_t ws_size,
                              hipStream_t stream) {
    const float* obs  = (const float*)d_in[0];
    const float* obst = (const float*)d_in[1];
    const float* eps  = (const float*)d_in[2];
    const float* W1   = (const float*)d_in[3];
    const float* b1   = (const float*)d_in[4];
    const float* W2   = (const float*)d_in[5];
    const float* b2   = (const float*)d_in[6];
    const float* muW  = (const float*)d_in[7];
    const float* mub  = (const float*)d_in[8];
    const float* lsW  = (const float*)d_in[9];
    const float* lsb  = (const float*)d_in[10];
    float* out = (float*)d_out;
    unsigned short* W2p = (unsigned short*)d_ws;   // 128 KB scratch

    w2prep_kernel<<<32, 256, 0, stream>>>(W2, W2p);
    actor_kernel<<<512, 512, 0, stream>>>(obs, obst, eps, W1, b1, b2,
                                          muW, mub, lsW, lsb, W2p, out);
}